// Round 9
// baseline (329.814 us; speedup 1.0000x reference)
//
#include <hip/hip_runtime.h>

constexpr int kB = 32;      // batch
constexpr int kA = 8400;    // anchors total (80*80 + 40*40 + 20*20)
constexpr int kG = 60;      // max GTs
constexpr int kC = 80;      // classes
constexpr int kK = 10;      // top-k
constexpr int kQ = 15;      // g-quads per batch (kG/4)

// ---- HW-native fast math ----
__device__ __forceinline__ float fexp(float x){ return __expf(x); }
__device__ __forceinline__ float flog(float x){ return __logf(x); }
__device__ __forceinline__ float frcp(float x){ return __builtin_amdgcn_rcpf(x); }
__device__ __forceinline__ float frsq(float x){ return __builtin_amdgcn_rsqf(x); }
__device__ __forceinline__ float fsqrt(float x){ return __builtin_amdgcn_sqrtf(x); }
__device__ __forceinline__ float fdiv(float a, float b){ return a * __builtin_amdgcn_rcpf(b); }
__device__ __forceinline__ float sigm(float x){ return frcp(1.0f + fexp(-x)); }
__device__ __forceinline__ float bce(float x, float t){
  return fmaxf(x, 0.0f) - x*t + flog(1.0f + fexp(-fabsf(x)));
}

// monotone float -> u32 (total order)
__device__ __forceinline__ unsigned ordbits(float v){
  unsigned u = __float_as_uint(v);
  return (u & 0x80000000u) ? ~u : (u | 0x80000000u);
}
__device__ __forceinline__ float unpackf(unsigned k){
  return __uint_as_float((k & 0x80000000u) ? (k & 0x7fffffffu) : ~k);
}

struct AInfo { int x, y; float st; };
__device__ __forceinline__ AInfo ainfo(int a){
  AInfo r;
  if (a < 6400)      { r.x = a % 80;           r.y = a / 80;           r.st = 8.0f;  }
  else if (a < 8000) { int l = a-6400; r.x = l % 40; r.y = l / 40;     r.st = 16.0f; }
  else               { int l = a-8000; r.x = l % 20; r.y = l / 20;     r.st = 32.0f; }
  return r;
}

__device__ __forceinline__ float featv(const float* __restrict__ f8,
                                       const float* __restrict__ f16,
                                       const float* __restrict__ f32x,
                                       int b, int ch, int a){
  if (a < 6400) return f8 [(b*85 + ch)*6400 + a];
  if (a < 8000) return f16[(b*85 + ch)*1600 + (a - 6400)];
  return             f32x[(b*85 + ch)*400  + (a - 8000)];
}

__device__ __forceinline__ float pair_iou(float4 g, float4 p){
  float tlx = fmaxf(g.x - g.z*0.5f, p.x - p.z*0.5f);
  float tly = fmaxf(g.y - g.w*0.5f, p.y - p.w*0.5f);
  float brx = fminf(g.x + g.z*0.5f, p.x + p.z*0.5f);
  float bry = fminf(g.y + g.w*0.5f, p.y + p.w*0.5f);
  float inter = (tlx < brx && tly < bry) ? (brx-tlx)*(bry-tly) : 0.0f;
  return fdiv(inter, g.z*g.w + p.z*p.w - inter + 1e-16f);
}

// cost given precomputed iou and obj sigmoid — shared by assign / conflict paths
__device__ __forceinline__ float cost_core(float iou, float cl, float obs, float b0sum,
                                           int a, float4 gt, int fg_a){
  AInfo ai = ainfo(a);
  float cx = ((float)ai.x + 0.5f)*ai.st;
  float cy = ((float)ai.y + 0.5f)*ai.st;
  bool in_box = (cx > gt.x - 0.5f*gt.z) && (cx < gt.x + 0.5f*gt.z)
             && (cy > gt.y - 0.5f*gt.w) && (cy < gt.y + 0.5f*gt.w);
  bool in_ctr = (cx > gt.x - 2.5f*ai.st) && (cx < gt.x + 2.5f*ai.st)
             && (cy > gt.y - 2.5f*ai.st) && (cy < gt.y + 2.5f*ai.st);
  float p = fsqrt(sigm(cl) * obs);
  p = fminf(fmaxf(p, 1e-7f), 1.0f - 1e-7f);
  float diff = -flog(p) + flog(1.0f - p);      // bce1 - bce0 at class cls
  float c = b0sum + diff;
  c += 3.0f * (-flog(iou + 1e-8f));
  c += (in_box && in_ctr) ? 0.0f : 100000.0f;
  c += fg_a ? 0.0f : 1000000000.0f;
  return c;
}

__device__ __forceinline__ void insert10(unsigned long long* arr, unsigned long long key){
  if (key > arr[kK-1]){
    arr[kK-1] = key;
    #pragma unroll
    for (int i = kK-1; i > 0; --i)
      if (arr[i] > arr[i-1]){ unsigned long long t = arr[i]; arr[i] = arr[i-1]; arr[i-1] = t; }
  }
}

__device__ __forceinline__ unsigned long long wave_max64(unsigned long long v){
  #pragma unroll
  for (int off = 32; off; off >>= 1){
    unsigned long long o = __shfl_xor(v, off, 64);
    if (o > v) v = o;
  }
  return v;
}

__global__ __launch_bounds__(256) void k_decode(
    const float* __restrict__ f8, const float* __restrict__ f16, const float* __restrict__ f32x,
    const float* __restrict__ gtb, const int* __restrict__ ngts,
    float* __restrict__ boxes, float* __restrict__ objl, float* __restrict__ b0s,
    float* __restrict__ bceS, float* __restrict__ obsA,
    int* __restrict__ fg, int* __restrict__ cnt, int* __restrict__ mtch,
    int* __restrict__ done, int* __restrict__ fin){
  int b = blockIdx.y;
  int tid = threadIdx.x;
  int a = blockIdx.x*256 + tid;
  if (blockIdx.x == 0 && b == 0){       // zero K3's coordination counters
    if (tid < kB) done[tid] = 0;
    if (tid == kB) fin[0] = 0;
  }
  __shared__ float4 sg[kG];
  if (tid < kG) sg[tid] = ((const float4*)gtb)[b*kG + tid];
  __syncthreads();
  if (a >= kA) return;
  int ng = ngts[b];
  const float* base; int hw, off; float st_; int gx, gy;
  if (a < 6400)      { base=f8;   hw=6400; off=a;        st_=8.0f;  gx=off%80; gy=off/80; }
  else if (a < 8000) { base=f16;  hw=1600; off=a-6400;   st_=16.0f; gx=off%40; gy=off/40; }
  else               { base=f32x; hw=400;  off=a-8000;   st_=32.0f; gx=off%20; gy=off/20; }
  const float* p0 = base + ((size_t)b*85)*hw + off;
  float t0 = p0[0];
  float t1 = p0[(size_t)hw];
  float t2 = p0[(size_t)2*hw];
  float t3 = p0[(size_t)3*hw];
  float ob = p0[(size_t)4*hw];
  float4 bx;
  bx.x = (t0 + (float)gx) * st_;
  bx.y = (t1 + (float)gy) * st_;
  bx.z = fexp(t2) * st_;
  bx.w = fexp(t3) * st_;
  int idx = b*kA + a;
  ((float4*)boxes)[idx] = bx;
  objl[idx] = ob;
  float obs = sigm(ob);
  obsA[idx] = obs;
  // sigm(cl)*obs = obs/v, v=1+e^-cl => p = sqrt(obs)*rsqrt(v); bce(cl,0)=cl+log(v)
  float so = fsqrt(obs);
  float s = 0.0f, sumCl = 0.0f, slogv = 0.0f;
  const float* pc = p0 + (size_t)5*hw;
  #pragma unroll 2
  for (int grp = 0; grp < kC/8; ++grp){
    float prodS = 1.0f, prodV = 1.0f;
    #pragma unroll
    for (int j = 0; j < 8; ++j){
      float cl = pc[(size_t)(grp*8 + j)*hw];
      float u = fexp(-cl);
      float v = 1.0f + u;
      float p = so * frsq(v);
      p = fminf(fmaxf(p, 1e-7f), 1.0f - 1e-7f);
      prodS *= (1.0f - p);
      prodV *= v;
      sumCl += cl;
    }
    s -= flog(prodS);
    slogv += flog(prodV);
  }
  b0s[idx] = s;
  bceS[idx] = sumCl + slogv;
  float cx = ((float)gx + 0.5f)*st_;
  float cy = ((float)gy + 0.5f)*st_;
  int f = 0;
  for (int g = 0; g < ng; ++g){
    float4 gt = sg[g];
    bool in_box = (cx > gt.x - 0.5f*gt.z) && (cx < gt.x + 0.5f*gt.z)
               && (cy > gt.y - 0.5f*gt.w) && (cy < gt.y + 0.5f*gt.w);
    bool in_ctr = (cx > gt.x - 2.5f*st_) && (cx < gt.x + 2.5f*st_)
               && (cy > gt.y - 2.5f*st_) && (cy < gt.y + 2.5f*st_);
    if (in_box || in_ctr){ f = 1; break; }
  }
  fg[idx] = f;
  cnt[idx] = 0;
  mtch[idx] = 0x7fffffff;
}

// ordered compaction of fg anchors: 256 threads/batch, wave shuffle-scan, 1 barrier
__global__ __launch_bounds__(256) void k_compact(
    const int* __restrict__ fg, unsigned short* __restrict__ alist, int* __restrict__ mcnt){
  int b = blockIdx.x;
  int tid = threadIdx.x;
  int lane = tid & 63, wid = tid >> 6;
  const int CH = 33;                      // ceil(8400/256)
  int start = tid*CH;
  unsigned long long bits = 0ull;
  int cl = 0;
  #pragma unroll
  for (int j = 0; j < CH; ++j){
    int a = start + j;
    int f = (a < kA) ? fg[b*kA + a] : 0;
    bits |= ((unsigned long long)(f & 1)) << j;
    cl += f;
  }
  int incl = cl;
  #pragma unroll
  for (int off = 1; off < 64; off <<= 1){
    int o = __shfl_up(incl, off, 64);
    if (lane >= off) incl += o;
  }
  __shared__ int swt[4];
  if (lane == 63) swt[wid] = incl;
  __syncthreads();
  int base = 0;
  for (int w = 0; w < 4; ++w) if (w < wid) base += swt[w];
  int o = base + incl - cl;               // exclusive prefix
  unsigned short* out = alist + (size_t)b*kA;
  #pragma unroll 1
  for (int j = 0; j < CH; ++j){
    if ((bits >> j) & 1ull) out[o++] = (unsigned short)(start + j);
  }
  if (tid == 0) mcnt[b] = swt[0] + swt[1] + swt[2] + swt[3];
}

// fused: per-wave SimOTA assign (4 GT rows/block) + last-block-per-batch loss
// + last-batch final reduce. NO early returns (barrier safety).
__global__ __launch_bounds__(256) void k_assign_loss(
    const float* __restrict__ f8, const float* __restrict__ f16, const float* __restrict__ f32x,
    const float* __restrict__ gtb, const int* __restrict__ gtc, const int* __restrict__ ngts,
    const float* __restrict__ boxes, const float* __restrict__ objl, const float* __restrict__ b0s,
    const float* __restrict__ bceS, const float* __restrict__ obsA,
    const int* __restrict__ fg, const unsigned short* __restrict__ alist, const int* __restrict__ mcnt,
    int* __restrict__ cnt, int* __restrict__ mtch,
    int* __restrict__ done, int* __restrict__ fin, float4* __restrict__ pacc,
    float* __restrict__ out){
  int b = blockIdx.x / kQ;
  int quad = blockIdx.x % kQ;
  int tid = threadIdx.x;
  int lane = tid & 63, wid = tid >> 6;
  int g = quad*4 + wid;                 // this wave's GT row
  int ng = ngts[b];

  // ================= assign phase: one wave per (b,g), barrier-free =================
  if (g < ng){
    float4 gt = ((const float4*)gtb)[b*kG + g];
    int cls = gtc[b*kG + g];
    const float4* bx4 = (const float4*)boxes;
    const float* c8  = f8   + ((size_t)b*85 + 5 + cls)*6400;
    const float* c16 = f16  + ((size_t)b*85 + 5 + cls)*1600;
    const float* c32 = f32x + ((size_t)b*85 + 5 + cls)*400;
    int m = mcnt[b];
    bool pushAll = (m < kK);
    const unsigned short* al = alist + (size_t)b*kA;

    unsigned long long k1[kK], k2[kK];
    #pragma unroll
    for (int i = 0; i < kK; ++i){ k1[i] = 0ull; k2[i] = 0ull; }

    for (int i = lane; i < m; i += 64){
      int a = (int)al[i];
      int idx = b*kA + a;
      float4 bx = bx4[idx];
      float iou = pair_iou(gt, bx);
      insert10(k1, ((unsigned long long)ordbits(iou) << 32) | (unsigned)(~a));
      AInfo ai = ainfo(a);
      float cx = ((float)ai.x + 0.5f)*ai.st;
      float cy = ((float)ai.y + 0.5f)*ai.st;
      bool in_box = (cx > gt.x - 0.5f*gt.z) && (cx < gt.x + 0.5f*gt.z)
                 && (cy > gt.y - 0.5f*gt.w) && (cy < gt.y + 0.5f*gt.w);
      bool in_ctr = (cx > gt.x - 2.5f*ai.st) && (cx < gt.x + 2.5f*ai.st)
                 && (cy > gt.y - 2.5f*ai.st) && (cy < gt.y + 2.5f*ai.st);
      if (pushAll || (in_box && in_ctr)){
        // in_both costs (<=~1362) strictly beat non-in_both (>=~99984):
        // per-lane top-10 suffices for global top-dynk (dynk<=9)
        float cl = (a < 6400) ? c8[a] : (a < 8000) ? c16[a-6400] : c32[a-8000];
        float c = cost_core(iou, cl, obsA[idx], b0s[idx], a, gt, 1);
        insert10(k2, ~(((unsigned long long)ordbits(c) << 32) | (unsigned)a));
      }
    }

    // pass-1: sum of top-10 iou (descending pop, matches jnp.top_k sum order)
    float ksum = 0.0f;
    #pragma unroll 1
    for (int k = 0; k < kK; ++k){
      unsigned long long best = wave_max64(k1[0]);
      if (k1[0] == best && best){
        #pragma unroll
        for (int i = 0; i < kK-1; ++i) k1[i] = k1[i+1];
        k1[kK-1] = 0ull;
      }
      if (best) ksum += unpackf((unsigned)(best >> 32));
    }
    int dynk = max((int)ksum, 1);       // truncation matches astype(int32)

    // pass-2: pop top-dynk min-cost (complemented keys)
    int my_a = -1;
    int taken = 0;
    #pragma unroll 1
    for (int k = 0; k < kK; ++k){
      if (k >= dynk) break;
      unsigned long long best = wave_max64(k2[0]);
      if (!best) break;
      if (k2[0] == best){
        #pragma unroll
        for (int i = 0; i < kK-1; ++i) k2[i] = k2[i+1];
        k2[kK-1] = 0ull;
      }
      if (lane == k) my_a = (int)((unsigned)(~best));
      ++taken;
    }
    if (!pushAll && taken < dynk){
      // rare: fewer in_both than dynk — augment with non-in_both fg by full cost
      #pragma unroll
      for (int i = 0; i < kK; ++i) k2[i] = 0ull;
      for (int i = lane; i < m; i += 64){
        int a = (int)al[i];
        int idx = b*kA + a;
        AInfo ai = ainfo(a);
        float cx = ((float)ai.x + 0.5f)*ai.st;
        float cy = ((float)ai.y + 0.5f)*ai.st;
        bool in_box = (cx > gt.x - 0.5f*gt.z) && (cx < gt.x + 0.5f*gt.z)
                   && (cy > gt.y - 0.5f*gt.w) && (cy < gt.y + 0.5f*gt.w);
        bool in_ctr = (cx > gt.x - 2.5f*ai.st) && (cx < gt.x + 2.5f*ai.st)
                   && (cy > gt.y - 2.5f*ai.st) && (cy < gt.y + 2.5f*ai.st);
        if (!(in_box && in_ctr)){
          float4 bx = bx4[idx];
          float iou = pair_iou(gt, bx);
          float cl = (a < 6400) ? c8[a] : (a < 8000) ? c16[a-6400] : c32[a-8000];
          float c = cost_core(iou, cl, obsA[idx], b0s[idx], a, gt, 1);
          insert10(k2, ~(((unsigned long long)ordbits(c) << 32) | (unsigned)a));
        }
      }
      #pragma unroll 1
      for (int k = taken; k < kK; ++k){
        if (k >= dynk) break;
        unsigned long long best = wave_max64(k2[0]);
        if (!best) break;
        if (k2[0] == best){
          #pragma unroll
          for (int i = 0; i < kK-1; ++i) k2[i] = k2[i+1];
          k2[kK-1] = 0ull;
        }
        if (lane == k) my_a = (int)((unsigned)(~best));
        ++taken;
      }
    }
    if (lane < taken && my_a >= 0){
      atomicAdd(&cnt[b*kA + my_a], 1);
      atomicMin(&mtch[b*kA + my_a], g);
    }
  }

  // ================= last-block-per-batch: loss for batch b =================
  __shared__ int sflag, sflag2;
  __syncthreads();
  if (tid == 0){
    __threadfence();                              // release our atomics
    int od = atomicAdd(&done[b], 1);
    sflag = (od == kQ - 1);
    sflag2 = 0;
  }
  __syncthreads();
  if (sflag){
    __threadfence();                              // acquire others' atomics
    __shared__ float4 sg[kG];
    __shared__ int scls[kG];
    if (tid < kG){ sg[tid] = ((const float4*)gtb)[b*kG + tid]; scls[tid] = gtc[b*kG + tid]; }
    __syncthreads();
    float li = 0.0f, lo = 0.0f, lc = 0.0f, nf = 0.0f;
    for (int a = tid; a < kA; a += 256){
      int idx = b*kA + a;
      int c = __hip_atomic_load(&cnt[idx], __ATOMIC_RELAXED, __HIP_MEMORY_SCOPE_AGENT);
      float ob = objl[idx];
      float4 bx = ((const float4*)boxes)[idx];
      float fgf = 0.0f; int mg = 0;
      if (c == 1){
        mg = __hip_atomic_load(&mtch[idx], __ATOMIC_RELAXED, __HIP_MEMORY_SCOPE_AGENT);
        fgf = 1.0f;
      }
      bool need = (c > 1);
      if (__any(need)){
        if (need){
          float b0 = b0s[idx];
          float obs = obsA[idx];
          int fga = fg[idx];
          float bestc = 3.0e38f; int bg = 0;
          for (int gg = 0; gg < ng; ++gg){
            float iou = pair_iou(sg[gg], bx);
            float cl = featv(f8,f16,f32x,b,5+scls[gg],a);
            float cst = cost_core(iou, cl, obs, b0, a, sg[gg], fga);
            if (cst < bestc){ bestc = cst; bg = gg; }   // strict <: jnp.argmin
          }
          mg = bg; fgf = 1.0f;
        }
      }
      lo += bce(ob, fgf*0.9f);
      if (fgf > 0.0f){
        nf += 1.0f;
        float4 r = sg[mg];
        float piou = pair_iou(r, bx);
        float tlx = fmaxf(bx.x - bx.z*0.5f, r.x - r.z*0.5f);
        float tly = fmaxf(bx.y - bx.w*0.5f, r.y - r.w*0.5f);
        float brx = fminf(bx.x + bx.z*0.5f, r.x + r.z*0.5f);
        float bry = fminf(bx.y + bx.w*0.5f, r.y + r.w*0.5f);
        float inter = (tlx < brx && tly < bry) ? (brx-tlx)*(bry-tly) : 0.0f;
        float un = bx.z*bx.w + r.z*r.w - inter;
        float iou = fdiv(inter, un + 1e-16f);
        li += 1.0f - iou*iou;
        int tc = scls[mg];
        float cl_tc = featv(f8,f16,f32x,b,5+tc,a);
        lc += bceS[idx] - piou * cl_tc;   // linearity of bce in target
      }
    }
    #pragma unroll
    for (int off = 32; off > 0; off >>= 1){
      li += __shfl_down(li, off, 64);
      lo += __shfl_down(lo, off, 64);
      lc += __shfl_down(lc, off, 64);
      nf += __shfl_down(nf, off, 64);
    }
    __shared__ float4 wred[4];
    if (lane == 0) wred[wid] = make_float4(li, lo, lc, nf);
    __syncthreads();
    if (tid == 0){
      float4 t = wred[0];
      for (int w = 1; w < 4; ++w){
        float4 o = wred[w];
        t.x += o.x; t.y += o.y; t.z += o.z; t.w += o.w;
      }
      pacc[b] = t;
      __threadfence();
      int fo = atomicAdd(fin, 1);
      sflag2 = (fo == kB - 1);
    }
    __syncthreads();
    if (sflag2){
      // ============== final: reduce 32 batch partials ==============
      if (wid == 0){
        __threadfence();
        float vx=0.f, vy=0.f, vz=0.f, vw=0.f;
        if (lane < kB){
          const float* pp = (const float*)&pacc[lane];
          vx = __hip_atomic_load(&pp[0], __ATOMIC_RELAXED, __HIP_MEMORY_SCOPE_AGENT);
          vy = __hip_atomic_load(&pp[1], __ATOMIC_RELAXED, __HIP_MEMORY_SCOPE_AGENT);
          vz = __hip_atomic_load(&pp[2], __ATOMIC_RELAXED, __HIP_MEMORY_SCOPE_AGENT);
          vw = __hip_atomic_load(&pp[3], __ATOMIC_RELAXED, __HIP_MEMORY_SCOPE_AGENT);
        }
        #pragma unroll
        for (int off = 32; off > 0; off >>= 1){
          vx += __shfl_down(vx, off, 64);
          vy += __shfl_down(vy, off, 64);
          vz += __shfl_down(vz, off, 64);
          vw += __shfl_down(vw, off, 64);
        }
        if (lane == 0) out[0] = (5.0f*vx + vy + vz) * frcp(fmaxf(vw, 1.0f));
      }
    }
  }
}

extern "C" void kernel_launch(void* const* d_in, const int* in_sizes, int n_in,
                              void* d_out, int out_size, void* d_ws, size_t ws_size,
                              hipStream_t stream) {
  (void)in_sizes; (void)n_in; (void)out_size; (void)ws_size;
  const float* f8   = (const float*)d_in[0];
  const float* f16  = (const float*)d_in[1];
  const float* f32x = (const float*)d_in[2];
  const float* gtb  = (const float*)d_in[3];
  const int*   gtc  = (const int*)d_in[4];
  const int*   ngts = (const int*)d_in[5];
  float* out = (float*)d_out;

  const size_t BA = (size_t)kB*kA;
  float* ws    = (float*)d_ws;
  float* boxes = ws;                              // 4*BA f32
  float* objl  = boxes + BA*4;
  float* b0s   = objl  + BA;
  float* bceS  = b0s   + BA;
  float* obsA  = bceS  + BA;
  int*   fg    = (int*)(obsA + BA);
  int*   cnt   = fg  + BA;
  int*   mtch  = cnt + BA;
  unsigned short* alist = (unsigned short*)(mtch + BA);  // BA u16
  int*   mcnt  = (int*)(alist + BA);              // kB
  int*   done  = mcnt + kB;                       // kB
  int*   fin   = done + kB;                       // 1 (+pad)
  float4* pacc = (float4*)(fin + 4);              // kB float4

  dim3 gBA((kA + 255)/256, kB);
  k_decode<<<gBA, dim3(256), 0, stream>>>(f8,f16,f32x,gtb,ngts,boxes,objl,b0s,bceS,obsA,fg,cnt,mtch,done,fin);
  k_compact<<<dim3(kB), dim3(256), 0, stream>>>(fg, alist, mcnt);
  k_assign_loss<<<dim3(kB*kQ), dim3(256), 0, stream>>>(
      f8,f16,f32x,gtb,gtc,ngts,boxes,objl,b0s,bceS,obsA,fg,alist,mcnt,cnt,mtch,done,fin,pacc,out);
}